// Round 11
// baseline (2260.190 us; speedup 1.0000x reference)
//
#include <hip/hip_runtime.h>
#include <math.h>

// MoE ViT forward. R7 base (2-barrier bf16-MFMA GEMM, fp32-B direct staging)
// + LN1 fused into qkv A-staging; row stats from a tiny deterministic kernel.
// B=8, S=197, D=768, NH=12, HD=64, E=4, HID=3072, DEPTH=12, NC=1000

#define BB 8
#define SS 197
#define DD 768
#define MT (BB*SS)      // 1576 tokens
#define NPATCH 196
#define MPE (BB*NPATCH) // 1568
#define HHID 3072
#define NEXP 4
#define QKVN 2304
#define SCW 228         // attn score-row stride

typedef __bf16 bf16_t;
typedef bf16_t bf16x4 __attribute__((ext_vector_type(4)));
typedef bf16_t bf16x8 __attribute__((ext_vector_type(8)));
typedef float  f32x4  __attribute__((ext_vector_type(4)));

__device__ __forceinline__ void gload16(const bf16_t* g, bf16_t* l) {
    __builtin_amdgcn_global_load_lds(
        (const __attribute__((address_space(1))) unsigned int*)g,
        (__attribute__((address_space(3))) unsigned int*)l,
        16, 0, 0);
}

__device__ __forceinline__ bf16x8 cvt8(float4 a, float4 b) {
    bf16x8 o;
    o[0]=(bf16_t)a.x; o[1]=(bf16_t)a.y; o[2]=(bf16_t)a.z; o[3]=(bf16_t)a.w;
    o[4]=(bf16_t)b.x; o[5]=(bf16_t)b.y; o[6]=(bf16_t)b.z; o[7]=(bf16_t)b.w;
    return o;
}

// ---------------- patch gather ----------------
__global__ void gather_patches(const float* __restrict__ x, bf16_t* __restrict__ Xp) {
    int i = blockIdx.x * 256 + threadIdx.x;
    if (i >= MPE * DD) return;
    int k = i % DD;
    int m = i / DD;
    int pw = k & 15, ph = (k >> 4) & 15, cin = k >> 8;
    int px = m % 14, py = (m / 14) % 14, b = m / NPATCH;
    int row = py * 16 + ph, col = px * 16 + pw;
    Xp[i] = (bf16_t)x[((size_t)(b * 3 + cin) * 224 + row) * 224 + col];
}

// ---------------- zero expert counters ----------------
__global__ void zero_cnt(int* __restrict__ cnt) {
    int i = threadIdx.x;
    if (i < 12*NEXP) cnt[i] = 0;
}

// ---------------- cls rows of h ----------------
__global__ void init_cls(const float* __restrict__ cls, const float* __restrict__ pos,
                         float* __restrict__ h) {
    int i = blockIdx.x * 256 + threadIdx.x;
    if (i >= BB * DD) return;
    int b = i / DD, d = i % DD;
    h[(size_t)(b * SS) * DD + d] = cls[d] + pos[d];
}

// ---------------- deterministic per-token row stats: one wave per token ----------------
__global__ __launch_bounds__(256) void row_stats(const float* __restrict__ x,
                                                 float* __restrict__ rs,
                                                 float* __restrict__ rq) {
    int wid = (blockIdx.x * 256 + threadIdx.x) >> 6;
    if (wid >= MT) return;
    int lane = threadIdx.x & 63;
    const float4* xr = (const float4*)(x + (size_t)wid * DD);
    float4 v0 = xr[lane], v1 = xr[lane + 64], v2 = xr[lane + 128];
    float s = v0.x+v0.y+v0.z+v0.w + v1.x+v1.y+v1.z+v1.w + v2.x+v2.y+v2.z+v2.w;
    float q = v0.x*v0.x+v0.y*v0.y+v0.z*v0.z+v0.w*v0.w
            + v1.x*v1.x+v1.y*v1.y+v1.z*v1.z+v1.w*v1.w
            + v2.x*v2.x+v2.y*v2.y+v2.z*v2.z+v2.w*v2.w;
    #pragma unroll
    for (int o = 32; o > 0; o >>= 1) { s += __shfl_xor(s, o); q += __shfl_xor(q, o); }
    if (lane == 0) { rs[wid] = s; rq[wid] = q; }
}

// ---------------- unified bf16-MFMA GEMM ----------------
// C = A @ B^T.  B fp32: BL=0 -> [N,K]; BL=1 -> [K,N] (in-flight transpose).
// ALN=0: A bf16 via global_load_lds. ALN=1: A fp32 reg-staged; blocks with
//        n0 < nsplit apply LN (lng,lnb, stats from rsumG/rsqG) during staging.
// MODE 2: fp32 C += v+bias; 3: gather, bf16 gelu(v+bias); 4: gather, fp32 C += (v+bias)*gv;
// MODE 5: bf16 store v+bias; 7: patch-embed row-remapped h store of v+bias+pos (pos via gv)
template<int BM, int BN, int WM, int WN, int MODE, int BL, int ALN>
__global__ __launch_bounds__((BM/WM)*(BN/WN)*64) void gemm_bf16(
    const void* __restrict__ Av, int nsplit,
    const float* __restrict__ Bw,
    const float* __restrict__ bias, float* __restrict__ C, bf16_t* __restrict__ Cb,
    const int* __restrict__ cnt, const int* __restrict__ idx,
    const float* __restrict__ gv,
    const float* __restrict__ lng, const float* __restrict__ lnb,
    const float* __restrict__ rsumG, const float* __restrict__ rsqG,
    int M, int N, int K)
{
    constexpr int NW  = (BM/WM)*(BN/WN);
    constexpr int NTH = NW * 64;
    constexpr int WNC = BN/WN;
    constexpr int MI  = WM/16;
    constexpr int NI  = WN/16;
    constexpr int IA  = (BM/8)/NW;       // A gload iters (ALN=0)
    constexpr int AT  = (BM*8)/NTH;      // A reg tasks (ALN=1)
    constexpr int BT  = (BN*8)/NTH;      // B reg tasks
    constexpr bool GATHER = (MODE == 3 || MODE == 4);

    int z = blockIdx.z;
    int count = GATHER ? cnt[z] : M;
    int m0 = blockIdx.y * BM;
    if (m0 >= count) return;
    int n0 = blockIdx.x * BN;
    const bf16_t* A  = (ALN == 0) ? (const bf16_t*)Av : nullptr;
    const float*  Ah = (ALN == 1) ? (const float*)Av  : nullptr;
    bool doLN = (ALN == 1) && (n0 < nsplit);
    Bw += (size_t)z * N * K;
    const float* biasz = bias ? (bias + (size_t)z * N) : nullptr;

    __shared__ bf16_t As[2][BM * 64];
    __shared__ bf16_t Bs[2][BN * 64];
    __shared__ int toks[BM];

    int tid = threadIdx.x, lane = tid & 63, w = tid >> 6;
    if (tid < BM) {
        int mm = m0 + tid;
        if (mm > count - 1) mm = count - 1;
        toks[tid] = GATHER ? idx[z * MT + mm] : mm;
    }
    __syncthreads();

    int wm = (w / WNC) * WM, wn = (w % WNC) * WN;
    int fr = lane & 15, fs = lane >> 4;

    f32x4 acc[MI][NI];
    #pragma unroll
    for (int mi = 0; mi < MI; mi++)
        #pragma unroll
        for (int ni = 0; ni < NI; ni++)
            #pragma unroll
            for (int j = 0; j < 4; j++) acc[mi][ni][j] = 0.f;

    int nk = K >> 6;
    int srow = lane >> 3, scc = lane & 7;

    float4 wA[BT], wB[BT];     // B NT staging regs
    float  bt[BT][8];          // B TN staging regs
    float4 xA[AT], xB[AT];     // A fp32 staging regs (ALN=1)
    float4 gA[AT], gB[AT], bA4[AT], bB4[AT];
    float  meanT[AT], rsT[AT];

    if (ALN == 1 && doLN) {
        #pragma unroll
        for (int i = 0; i < AT; i++) {
            int ar = (i*NTH + tid) >> 3;
            int tk = toks[ar];
            float s = rsumG[tk], q = rsqG[tk];
            float m = s * (1.0f/DD);
            float v = q * (1.0f/DD) - m*m;
            meanT[i] = m;
            rsT[i] = rsqrtf(v + 1e-5f);
        }
    }

    #define A_STAGE(buf, k0)                                                            \
        {                                                                               \
            _Pragma("unroll")                                                           \
            for (int i = 0; i < IA; i++) {                                              \
                int blk = i*NW + w;                                                     \
                int row = blk*8 + srow;                                                 \
                const bf16_t* s = A + (size_t)toks[row] * K + (k0) + ((scc ^ (row & 7)) << 3); \
                gload16(s, &As[buf][blk * 512]);                                        \
            }                                                                           \
        }

    #define A_LOAD_LN(k0)                                                               \
        {                                                                               \
            _Pragma("unroll")                                                           \
            for (int i = 0; i < AT; i++) {                                              \
                int task = i*NTH + tid;                                                 \
                int ar = task >> 3, sl = task & 7;                                      \
                const float* s = Ah + (size_t)toks[ar] * K + (k0) + sl*8;               \
                xA[i] = *(const float4*)s;                                              \
                xB[i] = *(const float4*)(s + 4);                                        \
                if (doLN) {                                                             \
                    gA[i]  = *(const float4*)(lng + (k0) + sl*8);                       \
                    gB[i]  = *(const float4*)(lng + (k0) + sl*8 + 4);                   \
                    bA4[i] = *(const float4*)(lnb + (k0) + sl*8);                       \
                    bB4[i] = *(const float4*)(lnb + (k0) + sl*8 + 4);                   \
                }                                                                       \
            }                                                                           \
        }

    #define A_WRITE_LN(buf)                                                             \
        {                                                                               \
            _Pragma("unroll")                                                           \
            for (int i = 0; i < AT; i++) {                                              \
                int task = i*NTH + tid;                                                 \
                int ar = task >> 3, sl = task & 7;                                      \
                float4 p0 = xA[i], p1 = xB[i];                                          \
                if (doLN) {                                                             \
                    float m = meanT[i], r = rsT[i];                                     \
                    p0.x = (p0.x - m)*r*gA[i].x + bA4[i].x;                             \
                    p0.y = (p0.y - m)*r*gA[i].y + bA4[i].y;                             \
                    p0.z = (p0.z - m)*r*gA[i].z + bA4[i].z;                             \
                    p0.w = (p0.w - m)*r*gA[i].w + bA4[i].w;                             \
                    p1.x = (p1.x - m)*r*gB[i].x + bB4[i].x;                             \
                    p1.y = (p1.y - m)*r*gB[i].y + bB4[i].y;                             \
                    p1.z = (p1.z - m)*r*gB[i].z + bB4[i].z;                             \
                    p1.w = (p1.w - m)*r*gB[i].w + bB4[i].w;                             \
                }                                                                       \
                *(bf16x8*)&As[buf][ar * 64 + ((sl ^ (ar & 7)) << 3)] = cvt8(p0, p1);    \
            }                                                                           \
        }

    #define B_LOAD(k0)                                                                  \
        {                                                                               \
            _Pragma("unroll")                                                           \
            for (int i = 0; i < BT; i++) {                                              \
                int task = i*NTH + tid;                                                 \
                if (BL == 0) {                                                          \
                    int row = task >> 3, sl = task & 7;                                 \
                    const float* s = Bw + (size_t)(n0 + row) * K + (k0) + sl*8;         \
                    wA[i] = *(const float4*)s;                                          \
                    wB[i] = *(const float4*)(s + 4);                                    \
                } else {                                                                \
                    int n = task & (BN-1), sl = task / BN;                              \
                    const float* s = Bw + (size_t)((k0) + sl*8) * N + n0 + n;           \
                    _Pragma("unroll")                                                   \
                    for (int j = 0; j < 8; j++) bt[i][j] = s[(size_t)j * N];            \
                }                                                                       \
            }                                                                           \
        }

    #define B_WRITE(buf)                                                                \
        {                                                                               \
            _Pragma("unroll")                                                           \
            for (int i = 0; i < BT; i++) {                                              \
                int task = i*NTH + tid;                                                 \
                int row, sl;                                                            \
                bf16x8 o;                                                               \
                if (BL == 0) {                                                          \
                    row = task >> 3; sl = task & 7;                                     \
                    o = cvt8(wA[i], wB[i]);                                             \
                } else {                                                                \
                    row = task & (BN-1); sl = task / BN;                                \
                    _Pragma("unroll")                                                   \
                    for (int j = 0; j < 8; j++) o[j] = (bf16_t)bt[i][j];                \
                }                                                                       \
                *(bf16x8*)&Bs[buf][row * 64 + ((sl ^ (row & 7)) << 3)] = o;             \
            }                                                                           \
        }

    if (ALN == 1) { A_LOAD_LN(0); } else { A_STAGE(0, 0); }
    B_LOAD(0);
    if (ALN == 1) { A_WRITE_LN(0); }
    B_WRITE(0);
    __syncthreads();
    int cur = 0;
    for (int t = 0; t < nk; t++) {
        if (t + 1 < nk) {
            if (ALN == 1) { A_LOAD_LN((t + 1) << 6); } else { A_STAGE(cur ^ 1, (t + 1) << 6); }
            B_LOAD((t + 1) << 6);
        }
        #pragma unroll
        for (int ks = 0; ks < 2; ks++) {
            bf16x8 af[MI], bfr[NI];
            #pragma unroll
            for (int mi = 0; mi < MI; mi++) {
                int r = wm + mi * 16 + fr;
                af[mi] = *(bf16x8*)&As[cur][r * 64 + (((fs + ks*4) ^ (r & 7)) << 3)];
            }
            #pragma unroll
            for (int ni = 0; ni < NI; ni++) {
                int r = wn + ni * 16 + fr;
                bfr[ni] = *(bf16x8*)&Bs[cur][r * 64 + (((fs + ks*4) ^ (r & 7)) << 3)];
            }
            #pragma unroll
            for (int mi = 0; mi < MI; mi++)
                #pragma unroll
                for (int ni = 0; ni < NI; ni++)
                    acc[mi][ni] = __builtin_amdgcn_mfma_f32_16x16x32_bf16(af[mi], bfr[ni], acc[mi][ni], 0, 0, 0);
        }
        if (t + 1 < nk) {
            if (ALN == 1) { A_WRITE_LN(cur ^ 1); }
            B_WRITE(cur ^ 1);
        }
        __syncthreads();
        cur ^= 1;
    }
    #undef A_STAGE
    #undef A_LOAD_LN
    #undef A_WRITE_LN
    #undef B_LOAD
    #undef B_WRITE

    #pragma unroll
    for (int mi = 0; mi < MI; mi++) {
        #pragma unroll
        for (int j = 0; j < 4; j++) {
            int rr = wm + mi * 16 + fs * 4 + j;
            if (m0 + rr >= count) continue;
            int crow = toks[rr];
            #pragma unroll
            for (int ni = 0; ni < NI; ni++) {
                int col = n0 + wn + ni * 16 + fr;
                float v = acc[mi][ni][j];
                if (MODE >= 2) v += biasz[col];
                if (MODE == 2) {
                    C[(size_t)crow * N + col] += v;
                } else if (MODE == 3) {
                    float g = 0.5f * v * (1.0f + tanhf(0.7978845608028654f * (v + 0.044715f * v * v * v)));
                    Cb[(size_t)crow * N + col] = (bf16_t)g;
                } else if (MODE == 4) {
                    C[(size_t)crow * N + col] += v * gv[crow];
                } else if (MODE == 5) {
                    Cb[(size_t)crow * N + col] = (bf16_t)v;
                } else if (MODE == 7) {
                    int bb = crow / NPATCH, p = crow - bb * NPATCH;
                    size_t o = ((size_t)(bb * SS + 1 + p)) * DD + col;
                    C[o] = v + gv[(size_t)(1 + p) * DD + col];   // gv == pos_embed
                }
            }
        }
    }
}

// ---------------- LN2 + gate: one wave per token ----------------
__global__ __launch_bounds__(256) void ln2_gate_kernel(const float* __restrict__ x,
                                                       const float* __restrict__ g,
                                                       const float* __restrict__ b,
                                                       const float* __restrict__ gw,
                                                       const float* __restrict__ gb,
                                                       bf16_t* __restrict__ yb,
                                                       float* __restrict__ gv,
                                                       int* __restrict__ cnt,
                                                       int* __restrict__ idxb)
{
    int wid = (blockIdx.x * 256 + threadIdx.x) >> 6;
    if (wid >= MT) return;
    int lane = threadIdx.x & 63;
    const float4* xr = (const float4*)(x + (size_t)wid * DD);
    float4 v0 = xr[lane], v1 = xr[lane + 64], v2 = xr[lane + 128];
    float s = v0.x+v0.y+v0.z+v0.w + v1.x+v1.y+v1.z+v1.w + v2.x+v2.y+v2.z+v2.w;
    #pragma unroll
    for (int o = 32; o > 0; o >>= 1) s += __shfl_xor(s, o);
    float mean = s * (1.0f/DD);
    float s2 = 0.f;
    #pragma unroll
    for (int c = 0; c < 3; c++) {
        float4 v = c == 0 ? v0 : (c == 1 ? v1 : v2);
        float dx = v.x-mean, dy = v.y-mean, dz = v.z-mean, dw = v.w-mean;
        s2 += dx*dx + dy*dy + dz*dz + dw*dw;
    }
    #pragma unroll
    for (int o = 32; o > 0; o >>= 1) s2 += __shfl_xor(s2, o);
    float rsv = rsqrtf(s2 * (1.0f/DD) + 1e-5f);
    const float4* gr = (const float4*)g;
    const float4* br = (const float4*)b;
    float p0 = 0.f, p1 = 0.f, p2 = 0.f, p3 = 0.f;
    #pragma unroll
    for (int c = 0; c < 3; c++) {
        float4 v = c == 0 ? v0 : (c == 1 ? v1 : v2);
        float4 gg = gr[lane + 64*c], bb = br[lane + 64*c];
        float y0 = (v.x - mean) * rsv * gg.x + bb.x;
        float y1 = (v.y - mean) * rsv * gg.y + bb.y;
        float y2 = (v.z - mean) * rsv * gg.z + bb.z;
        float y3 = (v.w - mean) * rsv * gg.w + bb.w;
        bf16x4 o; o[0]=(bf16_t)y0; o[1]=(bf16_t)y1; o[2]=(bf16_t)y2; o[3]=(bf16_t)y3;
        *(bf16x4*)(yb + (size_t)wid * DD + (lane + 64*c) * 4) = o;
        int off = lane + 64*c;
        float4 w0 = ((const float4*)(gw          ))[off];
        float4 w1v = ((const float4*)(gw +   DD  ))[off];
        float4 w2v = ((const float4*)(gw + 2*DD  ))[off];
        float4 w3v = ((const float4*)(gw + 3*DD  ))[off];
        p0 += y0*w0.x + y1*w0.y + y2*w0.z + y3*w0.w;
        p1 += y0*w1v.x + y1*w1v.y + y2*w1v.z + y3*w1v.w;
        p2 += y0*w2v.x + y1*w2v.y + y2*w2v.z + y3*w2v.w;
        p3 += y0*w3v.x + y1*w3v.y + y2*w3v.z + y3*w3v.w;
    }
    #pragma unroll
    for (int o = 32; o > 0; o >>= 1) {
        p0 += __shfl_xor(p0, o); p1 += __shfl_xor(p1, o);
        p2 += __shfl_xor(p2, o); p3 += __shfl_xor(p3, o);
    }
    if (lane == 0) {
        float l0 = p0 + gb[0], l1 = p1 + gb[1], l2 = p2 + gb[2], l3 = p3 + gb[3];
        int top = 0; float best = l0;
        if (l1 > best) { best = l1; top = 1; }
        if (l2 > best) { best = l2; top = 2; }
        if (l3 > best) { best = l3; top = 3; }
        float Z = __expf(l0-best) + __expf(l1-best) + __expf(l2-best) + __expf(l3-best);
        gv[wid] = 1.0f / Z;
        int pos = atomicAdd(&cnt[top], 1);
        idxb[top * MT + pos] = wid;
    }
}

// ---------------- MFMA attention: block per (q-tile, head, batch) ----------------
__global__ __launch_bounds__(256) void attn_kernel(const bf16_t* __restrict__ qkv,
                                                   bf16_t* __restrict__ ob)
{
    int qt = blockIdx.x, hh = blockIdx.y, b = blockIdx.z;
    __shared__ bf16_t Qs[64 * 64];
    __shared__ bf16_t KV[64 * 68];
    __shared__ float  Sc[64 * SCW];
    __shared__ float  linv[64];

    int tid = threadIdx.x, lane = tid & 63, w = tid >> 6;
    int wm = (w >> 1) * 32, wn = (w & 1) * 32;
    int fr = lane & 15, fs = lane >> 4;

    #pragma unroll
    for (int it = 0; it < 2; it++) {
        int row = 8*(it*4 + w) + (lane >> 3), cc = lane & 7;
        int q = qt*64 + row; if (q > SS-1) q = SS-1;
        const bf16_t* src = qkv + ((size_t)(b*SS + q))*QKVN + hh*64 + ((cc ^ (row & 7)) << 3);
        gload16(src, &Qs[(it*4 + w) * 512]);
    }

    for (int kt = 0; kt < 4; kt++) {
        __syncthreads();
        #pragma unroll
        for (int it = 0; it < 2; it++) {
            int row = 8*(it*4 + w) + (lane >> 3), cc = lane & 7;
            int k = kt*64 + row; if (k > SS-1) k = SS-1;
            const bf16_t* src = qkv + ((size_t)(b*SS + k))*QKVN + 768 + hh*64 + ((cc ^ (row & 7)) << 3);
            gload16(src, &KV[(it*4 + w) * 512]);
        }
        __syncthreads();
        f32x4 acc[2][2];
        #pragma unroll
        for (int mi = 0; mi < 2; mi++)
            #pragma unroll
            for (int ni = 0; ni < 2; ni++)
                #pragma unroll
                for (int j = 0; j < 4; j++) acc[mi][ni][j] = 0.f;
        #pragma unroll
        for (int ks = 0; ks < 2; ks++) {
            bf16x8 af[2], bfr[2];
            #pragma unroll
            for (int mi = 0; mi < 2; mi++) {
                int r = wm + mi * 16 + fr;
                af[mi] = *(bf16x8*)&Qs[r * 64 + (((fs + ks*4) ^ (r & 7)) << 3)];
            }
            #pragma unroll
            for (int ni = 0; ni < 2; ni++) {
                int r = wn + ni * 16 + fr;
                bfr[ni] = *(bf16x8*)&KV[r * 64 + (((fs + ks*4) ^ (r & 7)) << 3)];
            }
            #pragma unroll
            for (int mi = 0; mi < 2; mi++)
                #pragma unroll
                for (int ni = 0; ni < 2; ni++)
                    acc[mi][ni] = __builtin_amdgcn_mfma_f32_16x16x32_bf16(af[mi], bfr[ni], acc[mi][ni], 0, 0, 0);
        }
        #pragma unroll
        for (int mi = 0; mi < 2; mi++)
            #pragma unroll
            for (int j = 0; j < 4; j++) {
                int qr = wm + mi * 16 + fs * 4 + j;
                #pragma unroll
                for (int ni = 0; ni < 2; ni++) {
                    int col = kt*64 + wn + ni * 16 + fr;
                    if (col < SCW) {
                        float v = acc[mi][ni][j] * 0.125f;
                        if (col > SS-1) v = -1e30f;
                        Sc[qr * SCW + col] = v;
                    }
                }
            }
    }
    __syncthreads();

    {
        int row = tid >> 2, c = tid & 3;
        float m = -1e30f;
        for (int i = c; i < SCW; i += 4) m = fmaxf(m, Sc[row * SCW + i]);
        m = fmaxf(m, __shfl_xor(m, 1, 4));
        m = fmaxf(m, __shfl_xor(m, 2, 4));
        float s = 0.f;
        for (int i = c; i < SCW; i += 4) {
            float e = __expf(Sc[row * SCW + i] - m);
            Sc[row * SCW + i] = e;
            s += e;
        }
        s += __shfl_xor(s, 1, 4);
        s += __shfl_xor(s, 2, 4);
        if (c == 0) linv[row] = 1.0f / s;
    }

    f32x4 pv[2][2];
    #pragma unroll
    for (int mi = 0; mi < 2; mi++)
        #pragma unroll
        for (int ni = 0; ni < 2; ni++)
            #pragma unroll
            for (int j = 0; j < 4; j++) pv[mi][ni][j] = 0.f;

    for (int kt = 0; kt < 4; kt++) {
        __syncthreads();
        {
            int s = tid >> 2, c2 = tid & 3;
            int k = kt*64 + s; if (k > SS-1) k = SS-1;
            const bf16_t* vr = qkv + ((size_t)(b*SS + k))*QKVN + 1536 + hh*64;
            bf16x8 v0 = *(const bf16x8*)(vr + c2*16);
            bf16x8 v1 = *(const bf16x8*)(vr + c2*16 + 8);
            #pragma unroll
            for (int j = 0; j < 8; j++) {
                KV[(c2*16 + j) * 68 + s]     = v0[j];
                KV[(c2*16 + 8 + j) * 68 + s] = v1[j];
            }
        }
        __syncthreads();
        #pragma unroll
        for (int ks = 0; ks < 2; ks++) {
            int s0 = kt*64 + ks*32;
            if (s0 > SS-1) continue;
            bf16x8 af[2], bfr[2];
            #pragma unroll
            for (int mi = 0; mi < 2; mi++) {
                int qr = wm + mi * 16 + fr;
                const float* p = &Sc[qr * SCW + s0 + fs * 8];
                af[mi] = cvt8(*(const float4*)p, *(const float4*)(p + 4));
            }
            #pragma unroll
            for (int ni = 0; ni < 2; ni++) {
                int d = wn + ni * 16 + fr;
                bfr[ni] = *(bf16x8*)&KV[d * 68 + ks*32 + fs*8];
            }
            #pragma unroll
            for (int mi = 0; mi < 2; mi++)
                #pragma unroll
                for (int ni = 0; ni < 2; ni++)
                    pv[mi][ni] = __builtin_amdgcn_mfma_f32_16x16x32_bf16(af[mi], bfr[ni], pv[mi][ni], 0, 0, 0);
        }
    }

    #pragma unroll
    for (int mi = 0; mi < 2; mi++)
        #pragma unroll
        for (int j = 0; j < 4; j++) {
            int qr = wm + mi * 16 + fs * 4 + j;
            int q = qt*64 + qr;
            if (q > SS-1) continue;
            float il = linv[qr];
            #pragma unroll
            for (int ni = 0; ni < 2; ni++) {
                int d = wn + ni * 16 + fr;
                ob[((size_t)(b*SS + q))*DD + hh*64 + d] = (bf16_t)(pv[mi][ni][j] * il);
            }
        }
}

// ---------------- classifier head ----------------
__global__ void head_kernel(const float* __restrict__ h, const float* __restrict__ hw,
                            const float* __restrict__ hb, float* __restrict__ out)
{
    int i = blockIdx.x * 256 + threadIdx.x;
    if (i >= BB * 1000) return;
    int b = i & 7, n = i >> 3;
    const float4* hr = (const float4*)(h + (size_t)(b * SS) * DD);
    const float4* wr = (const float4*)(hw + (size_t)n * DD);
    float s = 0.f;
    #pragma unroll 4
    for (int k = 0; k < DD/4; k++) {
        float4 a = hr[k], wv = wr[k];
        s += a.x*wv.x + a.y*wv.y + a.z*wv.z + a.w*wv.w;
    }
    out[b * 1000 + n] = s + hb[n];
}

extern "C" void kernel_launch(void* const* d_in, const int* in_sizes, int n_in,
                              void* d_out, int out_size, void* d_ws, size_t ws_size,
                              hipStream_t stream) {
    const float* x          = (const float*)d_in[0];
    const float* patch_w    = (const float*)d_in[1];
    const float* patch_b    = (const float*)d_in[2];
    const float* cls_token  = (const float*)d_in[3];
    const float* pos_embed  = (const float*)d_in[4];
    const float* ln1_g      = (const float*)d_in[5];
    const float* ln1_b      = (const float*)d_in[6];
    const float* ln2_g      = (const float*)d_in[7];
    const float* ln2_b      = (const float*)d_in[8];
    const float* attn_in_w  = (const float*)d_in[9];
    const float* attn_in_b  = (const float*)d_in[10];
    const float* attn_out_w = (const float*)d_in[11];
    const float* attn_out_b = (const float*)d_in[12];
    const float* gate_w     = (const float*)d_in[13];
    const float* gate_b     = (const float*)d_in[14];
    const float* w1         = (const float*)d_in[15];
    const float* b1         = (const float*)d_in[16];
    const float* w2         = (const float*)d_in[17];
    const float* b2         = (const float*)d_in[18];
    const float* head_w     = (const float*)d_in[19];
    const float* head_b     = (const float*)d_in[20];
    float* out = (float*)d_out;

    char* wsb = (char*)d_ws;
    auto alloc = [&](size_t bytes) { char* p = wsb; wsb += (bytes + 63) & ~63ULL; return p; };
    bf16_t* Xp     = (bf16_t*)alloc((size_t)MPE * DD * 2);
    float*  h      = (float*) alloc((size_t)MT * DD * 4);
    bf16_t* qkv_bf = (bf16_t*)alloc((size_t)MT * QKVN * 2);
    bf16_t* ob_bf  = (bf16_t*)alloc((size_t)MT * DD * 2);
    bf16_t* yb_bf  = (bf16_t*)alloc((size_t)MT * DD * 2);
    bf16_t* hd_bf  = (bf16_t*)alloc((size_t)MT * HHID * 2);
    float*  gv     = (float*) alloc((size_t)MT * 4);
    float*  rsum   = (float*) alloc((size_t)MT * 4);
    float*  rsq    = (float*) alloc((size_t)MT * 4);
    int*    cnt    = (int*)   alloc(12 * NEXP * 4);
    int*    idxb   = (int*)   alloc((size_t)12 * NEXP * MT * 4);

    dim3 blk(256);
    dim3 blk512(512);
    const int NOSPLIT = 1 << 30;

    zero_cnt<<<1, 64, 0, stream>>>(cnt);
    init_cls<<<(BB*DD + 255)/256, blk, 0, stream>>>(cls_token, pos_embed, h);
    gather_patches<<<(MPE*DD + 255)/256, blk, 0, stream>>>(x, Xp);
    // patch embed -> h rows s>=1 (bias=patch_b, pos via gv slot)
    gemm_bf16<64,64,32,32,7,0,0><<<dim3(12, 25, 1), blk, 0, stream>>>(
        Xp, NOSPLIT, patch_w, patch_b, h, nullptr, nullptr, nullptr, pos_embed,
        nullptr, nullptr, nullptr, nullptr, MPE, DD, DD);

    for (int i = 0; i < 12; i++) {
        const float* aw    = attn_in_w  + (size_t)i * QKVN * DD;
        const float* ow    = attn_out_w + (size_t)i * DD * DD;
        const float* w1l   = w1 + (size_t)i * NEXP * DD * HHID;
        const float* w2l   = w2 + (size_t)i * NEXP * HHID * DD;
        const float* ab    = attn_in_b  + (size_t)i * QKVN;
        const float* obias = attn_out_b + (size_t)i * DD;
        const float* l1g = ln1_g + (size_t)i * DD;
        const float* l1b = ln1_b + (size_t)i * DD;
        const float* l2g = ln2_g + (size_t)i * DD;
        const float* l2b = ln2_b + (size_t)i * DD;
        const float* gw  = gate_w + (size_t)i * NEXP * DD;
        const float* gb  = gate_b + (size_t)i * NEXP;
        const float* b1l = b1 + (size_t)i * NEXP * HHID;
        const float* b2l = b2 + (size_t)i * NEXP * DD;
        int* cnt_i  = cnt  + i * NEXP;
        int* idxb_i = idxb + (size_t)i * NEXP * MT;

        row_stats<<<dim3((MT*64 + 255)/256), blk, 0, stream>>>(h, rsum, rsq);
        // merged q|kv projection, LN1 fused into A-staging (LN for n0<768, plain cvt else)
        gemm_bf16<128,64,64,32,5,0,1><<<dim3(QKVN/64, 13, 1), blk, 0, stream>>>(
            h, DD, aw, ab, nullptr, qkv_bf, nullptr, nullptr, nullptr,
            l1g, l1b, rsum, rsq, MT, QKVN, DD);
        attn_kernel<<<dim3(4, 12, BB), blk, 0, stream>>>(qkv_bf, ob_bf);
        gemm_bf16<64,64,32,32,2,0,0><<<dim3(12, 25, 1), blk, 0, stream>>>(
            ob_bf, NOSPLIT, ow, obias, h, nullptr, nullptr, nullptr, nullptr,
            nullptr, nullptr, nullptr, nullptr, MT, DD, DD);
        ln2_gate_kernel<<<dim3((MT*64 + 255)/256), blk, 0, stream>>>(
            h, l2g, l2b, gw, gb, yb_bf, gv, cnt_i, idxb_i);
        // moe1: w1[i] fp32 [768,3072] per expert, transposed in-flight (TN)
        gemm_bf16<128,128,64,32,3,1,0><<<dim3(HHID/128, 13, NEXP), blk512, 0, stream>>>(
            yb_bf, NOSPLIT, w1l, b1l, nullptr, hd_bf, cnt_i, idxb_i, nullptr,
            nullptr, nullptr, nullptr, nullptr, MT, HHID, DD);
        // moe2: w2[i] fp32 [3072,768] per expert (TN) + residual
        gemm_bf16<64,64,32,32,4,1,0><<<dim3(12, 25, NEXP), blk, 0, stream>>>(
            hd_bf, NOSPLIT, w2l, b2l, h, nullptr, cnt_i, idxb_i, gv,
            nullptr, nullptr, nullptr, nullptr, MT, DD, HHID);
    }

    head_kernel<<<(BB*1000 + 255)/256, blk, 0, stream>>>(h, head_w, head_b, out);
}

// Round 12
// 2244.108 us; speedup vs baseline: 1.0072x; 1.0072x over previous
//
#include <hip/hip_runtime.h>
#include <math.h>

// MoE ViT forward. R7 base (2-barrier bf16-MFMA GEMM, fp32-B direct staging)
// with vectorized TN weight staging (float4 x4 + 4x4 reg transpose).
// B=8, S=197, D=768, NH=12, HD=64, E=4, HID=3072, DEPTH=12, NC=1000

#define BB 8
#define SS 197
#define DD 768
#define MT (BB*SS)      // 1576 tokens
#define NPATCH 196
#define MPE (BB*NPATCH) // 1568
#define HHID 3072
#define NEXP 4
#define QKVN 2304
#define SCW 228         // attn score-row stride

typedef __bf16 bf16_t;
typedef bf16_t bf16x4 __attribute__((ext_vector_type(4)));
typedef bf16_t bf16x8 __attribute__((ext_vector_type(8)));
typedef float  f32x4  __attribute__((ext_vector_type(4)));

__device__ __forceinline__ void gload16(const bf16_t* g, bf16_t* l) {
    __builtin_amdgcn_global_load_lds(
        (const __attribute__((address_space(1))) unsigned int*)g,
        (__attribute__((address_space(3))) unsigned int*)l,
        16, 0, 0);
}

__device__ __forceinline__ bf16x8 cvt8(float4 a, float4 b) {
    bf16x8 o;
    o[0]=(bf16_t)a.x; o[1]=(bf16_t)a.y; o[2]=(bf16_t)a.z; o[3]=(bf16_t)a.w;
    o[4]=(bf16_t)b.x; o[5]=(bf16_t)b.y; o[6]=(bf16_t)b.z; o[7]=(bf16_t)b.w;
    return o;
}

// ---------------- patch gather ----------------
__global__ void gather_patches(const float* __restrict__ x, bf16_t* __restrict__ Xp) {
    int i = blockIdx.x * 256 + threadIdx.x;
    if (i >= MPE * DD) return;
    int k = i % DD;
    int m = i / DD;
    int pw = k & 15, ph = (k >> 4) & 15, cin = k >> 8;
    int px = m % 14, py = (m / 14) % 14, b = m / NPATCH;
    int row = py * 16 + ph, col = px * 16 + pw;
    Xp[i] = (bf16_t)x[((size_t)(b * 3 + cin) * 224 + row) * 224 + col];
}

// ---------------- init: zero cnt + cls rows of h ----------------
__global__ void init_misc(const float* __restrict__ cls, const float* __restrict__ pos,
                          float* __restrict__ h, bf16_t* __restrict__ hb, int* __restrict__ cnt) {
    int i = blockIdx.x * 256 + threadIdx.x;
    if (i < 12*NEXP) cnt[i] = 0;
    if (i < BB * DD) {
        int b = i / DD, d = i % DD;
        float v = cls[d] + pos[d];
        size_t o = (size_t)(b * SS) * DD + d;
        h[o] = v;
        hb[o] = (bf16_t)v;
    }
}

// ---------------- unified bf16-MFMA GEMM, fp32-B direct staging ----------------
// C = A[M,K](bf16) @ B^T, B fp32: BL=0 -> [N,K] row-major; BL=1 -> [K,N] (transposed in-flight)
// MODE 2: fp32 C += v+bias; 3: gather, bf16 gelu(v+bias); 4: gather, fp32 C += (v+bias)*gv + bf16 mirror;
// MODE 5: bf16 store v+bias; 7: patch-embed: h/h_bf row-remapped store of v+bias+pos (pos via gv)
template<int BM, int BN, int WM, int WN, int MODE, int BL>
__global__ __launch_bounds__((BM/WM)*(BN/WN)*64) void gemm_bf16(
    const bf16_t* __restrict__ A, const bf16_t* __restrict__ A2, int nsplit,
    const float* __restrict__ Bw,
    const float* __restrict__ bias, float* __restrict__ C, bf16_t* __restrict__ Cb,
    const int* __restrict__ cnt, const int* __restrict__ idx,
    const float* __restrict__ gv, int M, int N, int K)
{
    constexpr int NW  = (BM/WM)*(BN/WN);
    constexpr int NTH = NW * 64;
    constexpr int WNC = BN/WN;
    constexpr int MI  = WM/16;
    constexpr int NI  = WN/16;
    constexpr int IA  = (BM/8)/NW;       // A gload iters
    constexpr int BT  = (BN*8)/NTH;      // B NT staging tasks per thread
    constexpr int NGL = __builtin_ctz(BN/4);   // log2(n-groups) for TN
    constexpr bool GATHER = (MODE == 3 || MODE == 4);

    int z = blockIdx.z;
    int count = GATHER ? cnt[z] : M;
    int m0 = blockIdx.y * BM;
    if (m0 >= count) return;
    int n0 = blockIdx.x * BN;
    if (n0 >= nsplit) A = A2;
    Bw += (size_t)z * N * K;
    const float* biasz = bias ? (bias + (size_t)z * N) : nullptr;

    __shared__ bf16_t As[2][BM * 64];
    __shared__ bf16_t Bs[2][BN * 64];
    __shared__ int toks[BM];

    int tid = threadIdx.x, lane = tid & 63, w = tid >> 6;
    if (tid < BM) {
        int mm = m0 + tid;
        if (mm > count - 1) mm = count - 1;
        toks[tid] = GATHER ? idx[z * MT + mm] : mm;
    }
    __syncthreads();

    int wm = (w / WNC) * WM, wn = (w % WNC) * WN;
    int fr = lane & 15, fs = lane >> 4;

    f32x4 acc[MI][NI];
    #pragma unroll
    for (int mi = 0; mi < MI; mi++)
        #pragma unroll
        for (int ni = 0; ni < NI; ni++)
            #pragma unroll
            for (int j = 0; j < 4; j++) acc[mi][ni][j] = 0.f;

    int nk = K >> 6;
    int srow = lane >> 3, scc = lane & 7;

    float4 wA[BT], wB[BT];                 // B NT staging regs
    float4 tq0, tq1, tq2, tq3;             // B TN staging regs (4 k-rows x 4 n)
    int n4B = (tid & ((BN >> 2) - 1)) << 2;  // TN: first of 4 consecutive n
    int kposB = tid >> NGL;                  // TN: k-quad index 0..15

    #define A_STAGE(buf, k0)                                                            \
        {                                                                               \
            _Pragma("unroll")                                                           \
            for (int i = 0; i < IA; i++) {                                              \
                int blk = i*NW + w;                                                     \
                int row = blk*8 + srow;                                                 \
                const bf16_t* s = A + (size_t)toks[row] * K + (k0) + ((scc ^ (row & 7)) << 3); \
                gload16(s, &As[buf][blk * 512]);                                        \
            }                                                                           \
        }

    #define B_LOAD(k0)                                                                  \
        {                                                                               \
            if (BL == 0) {                                                              \
                _Pragma("unroll")                                                       \
                for (int i = 0; i < BT; i++) {                                          \
                    int task = i*NTH + tid;                                             \
                    int row = task >> 3, sl = task & 7;                                 \
                    const float* s = Bw + (size_t)(n0 + row) * K + (k0) + sl*8;         \
                    wA[i] = *(const float4*)s;                                          \
                    wB[i] = *(const float4*)(s + 4);                                    \
                }                                                                       \
            } else {                                                                    \
                const float* s = Bw + (size_t)((k0) + kposB*4) * N + n0 + n4B;          \
                tq0 = *(const float4*)s;                                                \
                tq1 = *(const float4*)(s + N);                                          \
                tq2 = *(const float4*)(s + 2*N);                                        \
                tq3 = *(const float4*)(s + 3*N);                                        \
            }                                                                           \
        }

    #define B_WRITE(buf)                                                                \
        {                                                                               \
            if (BL == 0) {                                                              \
                _Pragma("unroll")                                                       \
                for (int i = 0; i < BT; i++) {                                          \
                    int task = i*NTH + tid;                                             \
                    int row = task >> 3, sl = task & 7;                                 \
                    *(bf16x8*)&Bs[buf][row * 64 + ((sl ^ (row & 7)) << 3)] = cvt8(wA[i], wB[i]); \
                }                                                                       \
            } else {                                                                    \
                int slot = kposB >> 1, off = (kposB & 1) * 4;                           \
                { bf16x4 o; o[0]=(bf16_t)tq0.x; o[1]=(bf16_t)tq1.x; o[2]=(bf16_t)tq2.x; o[3]=(bf16_t)tq3.x; \
                  int row = n4B;     *(bf16x4*)&Bs[buf][row*64 + ((slot ^ (row & 7)) << 3) + off] = o; } \
                { bf16x4 o; o[0]=(bf16_t)tq0.y; o[1]=(bf16_t)tq1.y; o[2]=(bf16_t)tq2.y; o[3]=(bf16_t)tq3.y; \
                  int row = n4B + 1; *(bf16x4*)&Bs[buf][row*64 + ((slot ^ (row & 7)) << 3) + off] = o; } \
                { bf16x4 o; o[0]=(bf16_t)tq0.z; o[1]=(bf16_t)tq1.z; o[2]=(bf16_t)tq2.z; o[3]=(bf16_t)tq3.z; \
                  int row = n4B + 2; *(bf16x4*)&Bs[buf][row*64 + ((slot ^ (row & 7)) << 3) + off] = o; } \
                { bf16x4 o; o[0]=(bf16_t)tq0.w; o[1]=(bf16_t)tq1.w; o[2]=(bf16_t)tq2.w; o[3]=(bf16_t)tq3.w; \
                  int row = n4B + 3; *(bf16x4*)&Bs[buf][row*64 + ((slot ^ (row & 7)) << 3) + off] = o; } \
            }                                                                           \
        }

    A_STAGE(0, 0);
    B_LOAD(0);
    B_WRITE(0);
    __syncthreads();
    int cur = 0;
    for (int t = 0; t < nk; t++) {
        if (t + 1 < nk) { A_STAGE(cur ^ 1, (t + 1) << 6); B_LOAD((t + 1) << 6); }
        #pragma unroll
        for (int ks = 0; ks < 2; ks++) {
            bf16x8 af[MI], bfr[NI];
            #pragma unroll
            for (int mi = 0; mi < MI; mi++) {
                int r = wm + mi * 16 + fr;
                af[mi] = *(bf16x8*)&As[cur][r * 64 + (((fs + ks*4) ^ (r & 7)) << 3)];
            }
            #pragma unroll
            for (int ni = 0; ni < NI; ni++) {
                int r = wn + ni * 16 + fr;
                bfr[ni] = *(bf16x8*)&Bs[cur][r * 64 + (((fs + ks*4) ^ (r & 7)) << 3)];
            }
            #pragma unroll
            for (int mi = 0; mi < MI; mi++)
                #pragma unroll
                for (int ni = 0; ni < NI; ni++)
                    acc[mi][ni] = __builtin_amdgcn_mfma_f32_16x16x32_bf16(af[mi], bfr[ni], acc[mi][ni], 0, 0, 0);
        }
        if (t + 1 < nk) B_WRITE(cur ^ 1);
        __syncthreads();
        cur ^= 1;
    }
    #undef A_STAGE
    #undef B_LOAD
    #undef B_WRITE

    #pragma unroll
    for (int mi = 0; mi < MI; mi++) {
        #pragma unroll
        for (int j = 0; j < 4; j++) {
            int rr = wm + mi * 16 + fs * 4 + j;
            if (m0 + rr >= count) continue;
            int crow = toks[rr];
            #pragma unroll
            for (int ni = 0; ni < NI; ni++) {
                int col = n0 + wn + ni * 16 + fr;
                float v = acc[mi][ni][j];
                if (MODE >= 2) v += biasz[col];
                if (MODE == 2) {
                    C[(size_t)crow * N + col] += v;
                } else if (MODE == 3) {
                    float g = 0.5f * v * (1.0f + tanhf(0.7978845608028654f * (v + 0.044715f * v * v * v)));
                    Cb[(size_t)crow * N + col] = (bf16_t)g;
                } else if (MODE == 4) {
                    float* p = &C[(size_t)crow * N + col];
                    float nv = *p + v * gv[crow];
                    *p = nv;
                    Cb[(size_t)crow * N + col] = (bf16_t)nv;
                } else if (MODE == 5) {
                    Cb[(size_t)crow * N + col] = (bf16_t)v;
                } else if (MODE == 7) {
                    int bb = crow / NPATCH, p = crow - bb * NPATCH;
                    size_t o = ((size_t)(bb * SS + 1 + p)) * DD + col;
                    float vv = v + gv[(size_t)(1 + p) * DD + col];   // gv == pos_embed
                    C[o] = vv;
                    Cb[o] = (bf16_t)vv;
                }
            }
        }
    }
}

// ---------------- LN1: one wave per token, writes qn bf16 ----------------
__global__ __launch_bounds__(256) void ln1_kernel(const float* __restrict__ x,
                                                  const float* __restrict__ g,
                                                  const float* __restrict__ b,
                                                  bf16_t* __restrict__ qn)
{
    int wid = (blockIdx.x * 256 + threadIdx.x) >> 6;
    if (wid >= MT) return;
    int lane = threadIdx.x & 63;
    const float4* xr = (const float4*)(x + (size_t)wid * DD);
    float4 v0 = xr[lane], v1 = xr[lane + 64], v2 = xr[lane + 128];
    float s = v0.x+v0.y+v0.z+v0.w + v1.x+v1.y+v1.z+v1.w + v2.x+v2.y+v2.z+v2.w;
    #pragma unroll
    for (int o = 32; o > 0; o >>= 1) s += __shfl_xor(s, o);
    float mean = s * (1.0f/DD);
    float s2 = 0.f;
    #pragma unroll
    for (int c = 0; c < 3; c++) {
        float4 v = c == 0 ? v0 : (c == 1 ? v1 : v2);
        float dx = v.x-mean, dy = v.y-mean, dz = v.z-mean, dw = v.w-mean;
        s2 += dx*dx + dy*dy + dz*dz + dw*dw;
    }
    #pragma unroll
    for (int o = 32; o > 0; o >>= 1) s2 += __shfl_xor(s2, o);
    float rs = rsqrtf(s2 * (1.0f/DD) + 1e-5f);
    const float4* gr = (const float4*)g;
    const float4* br = (const float4*)b;
    #pragma unroll
    for (int c = 0; c < 3; c++) {
        float4 v = c == 0 ? v0 : (c == 1 ? v1 : v2);
        float4 gg = gr[lane + 64*c], bb = br[lane + 64*c];
        bf16x4 o;
        o[0] = (bf16_t)((v.x - mean) * rs * gg.x + bb.x);
        o[1] = (bf16_t)((v.y - mean) * rs * gg.y + bb.y);
        o[2] = (bf16_t)((v.z - mean) * rs * gg.z + bb.z);
        o[3] = (bf16_t)((v.w - mean) * rs * gg.w + bb.w);
        *(bf16x4*)(qn + (size_t)wid * DD + (lane + 64*c) * 4) = o;
    }
}

// ---------------- LN2 + gate: one wave per token ----------------
__global__ __launch_bounds__(256) void ln2_gate_kernel(const float* __restrict__ x,
                                                       const float* __restrict__ g,
                                                       const float* __restrict__ b,
                                                       const float* __restrict__ gw,
                                                       const float* __restrict__ gb,
                                                       bf16_t* __restrict__ yb,
                                                       float* __restrict__ gv,
                                                       int* __restrict__ cnt,
                                                       int* __restrict__ idxb)
{
    int wid = (blockIdx.x * 256 + threadIdx.x) >> 6;
    if (wid >= MT) return;
    int lane = threadIdx.x & 63;
    const float4* xr = (const float4*)(x + (size_t)wid * DD);
    float4 v0 = xr[lane], v1 = xr[lane + 64], v2 = xr[lane + 128];
    float s = v0.x+v0.y+v0.z+v0.w + v1.x+v1.y+v1.z+v1.w + v2.x+v2.y+v2.z+v2.w;
    #pragma unroll
    for (int o = 32; o > 0; o >>= 1) s += __shfl_xor(s, o);
    float mean = s * (1.0f/DD);
    float s2 = 0.f;
    #pragma unroll
    for (int c = 0; c < 3; c++) {
        float4 v = c == 0 ? v0 : (c == 1 ? v1 : v2);
        float dx = v.x-mean, dy = v.y-mean, dz = v.z-mean, dw = v.w-mean;
        s2 += dx*dx + dy*dy + dz*dz + dw*dw;
    }
    #pragma unroll
    for (int o = 32; o > 0; o >>= 1) s2 += __shfl_xor(s2, o);
    float rs = rsqrtf(s2 * (1.0f/DD) + 1e-5f);
    const float4* gr = (const float4*)g;
    const float4* br = (const float4*)b;
    float p0 = 0.f, p1 = 0.f, p2 = 0.f, p3 = 0.f;
    #pragma unroll
    for (int c = 0; c < 3; c++) {
        float4 v = c == 0 ? v0 : (c == 1 ? v1 : v2);
        float4 gg = gr[lane + 64*c], bb = br[lane + 64*c];
        float y0 = (v.x - mean) * rs * gg.x + bb.x;
        float y1 = (v.y - mean) * rs * gg.y + bb.y;
        float y2 = (v.z - mean) * rs * gg.z + bb.z;
        float y3 = (v.w - mean) * rs * gg.w + bb.w;
        bf16x4 o; o[0]=(bf16_t)y0; o[1]=(bf16_t)y1; o[2]=(bf16_t)y2; o[3]=(bf16_t)y3;
        *(bf16x4*)(yb + (size_t)wid * DD + (lane + 64*c) * 4) = o;
        int off = lane + 64*c;
        float4 w0 = ((const float4*)(gw          ))[off];
        float4 w1v = ((const float4*)(gw +   DD  ))[off];
        float4 w2v = ((const float4*)(gw + 2*DD  ))[off];
        float4 w3v = ((const float4*)(gw + 3*DD  ))[off];
        p0 += y0*w0.x + y1*w0.y + y2*w0.z + y3*w0.w;
        p1 += y0*w1v.x + y1*w1v.y + y2*w1v.z + y3*w1v.w;
        p2 += y0*w2v.x + y1*w2v.y + y2*w2v.z + y3*w2v.w;
        p3 += y0*w3v.x + y1*w3v.y + y2*w3v.z + y3*w3v.w;
    }
    #pragma unroll
    for (int o = 32; o > 0; o >>= 1) {
        p0 += __shfl_xor(p0, o); p1 += __shfl_xor(p1, o);
        p2 += __shfl_xor(p2, o); p3 += __shfl_xor(p3, o);
    }
    if (lane == 0) {
        float l0 = p0 + gb[0], l1 = p1 + gb[1], l2 = p2 + gb[2], l3 = p3 + gb[3];
        int top = 0; float best = l0;
        if (l1 > best) { best = l1; top = 1; }
        if (l2 > best) { best = l2; top = 2; }
        if (l3 > best) { best = l3; top = 3; }
        float Z = __expf(l0-best) + __expf(l1-best) + __expf(l2-best) + __expf(l3-best);
        gv[wid] = 1.0f / Z;
        int pos = atomicAdd(&cnt[top], 1);
        idxb[top * MT + pos] = wid;
    }
}

// ---------------- MFMA attention: block per (q-tile, head, batch) ----------------
__global__ __launch_bounds__(256) void attn_kernel(const bf16_t* __restrict__ qkv,
                                                   bf16_t* __restrict__ ob)
{
    int qt = blockIdx.x, hh = blockIdx.y, b = blockIdx.z;
    __shared__ bf16_t Qs[64 * 64];
    __shared__ bf16_t KV[64 * 68];
    __shared__ float  Sc[64 * SCW];
    __shared__ float  linv[64];

    int tid = threadIdx.x, lane = tid & 63, w = tid >> 6;
    int wm = (w >> 1) * 32, wn = (w & 1) * 32;
    int fr = lane & 15, fs = lane >> 4;

    #pragma unroll
    for (int it = 0; it < 2; it++) {
        int row = 8*(it*4 + w) + (lane >> 3), cc = lane & 7;
        int q = qt*64 + row; if (q > SS-1) q = SS-1;
        const bf16_t* src = qkv + ((size_t)(b*SS + q))*QKVN + hh*64 + ((cc ^ (row & 7)) << 3);
        gload16(src, &Qs[(it*4 + w) * 512]);
    }

    for (int kt = 0; kt < 4; kt++) {
        __syncthreads();
        #pragma unroll
        for (int it = 0; it < 2; it++) {
            int row = 8*(it*4 + w) + (lane >> 3), cc = lane & 7;
            int k = kt*64 + row; if (k > SS-1) k = SS-1;
            const bf16_t* src = qkv + ((size_t)(b*SS + k))*QKVN + 768 + hh*64 + ((cc ^ (row & 7)) << 3);
            gload16(src, &KV[(it*4 + w) * 512]);
        }
        __syncthreads();
        f32x4 acc[2][2];
        #pragma unroll
        for (int mi = 0; mi < 2; mi++)
            #pragma unroll
            for (int ni = 0; ni < 2; ni++)
                #pragma unroll
                for (int j = 0; j < 4; j++) acc[mi][ni][j] = 0.f;
        #pragma unroll
        for (int ks = 0; ks < 2; ks++) {
            bf16x8 af[2], bfr[2];
            #pragma unroll
            for (int mi = 0; mi < 2; mi++) {
                int r = wm + mi * 16 + fr;
                af[mi] = *(bf16x8*)&Qs[r * 64 + (((fs + ks*4) ^ (r & 7)) << 3)];
            }
            #pragma unroll
            for (int ni = 0; ni < 2; ni++) {
                int r = wn + ni * 16 + fr;
                bfr[ni] = *(bf16x8*)&KV[r * 64 + (((fs + ks*4) ^ (r & 7)) << 3)];
            }
            #pragma unroll
            for (int mi = 0; mi < 2; mi++)
                #pragma unroll
                for (int ni = 0; ni < 2; ni++)
                    acc[mi][ni] = __builtin_amdgcn_mfma_f32_16x16x32_bf16(af[mi], bfr[ni], acc[mi][ni], 0, 0, 0);
        }
        #pragma unroll
        for (int mi = 0; mi < 2; mi++)
            #pragma unroll
            for (int j = 0; j < 4; j++) {
                int qr = wm + mi * 16 + fs * 4 + j;
                #pragma unroll
                for (int ni = 0; ni < 2; ni++) {
                    int col = kt*64 + wn + ni * 16 + fr;
                    if (col < SCW) {
                        float v = acc[mi][ni][j] * 0.125f;
                        if (col > SS-1) v = -1e30f;
                        Sc[qr * SCW + col] = v;
                    }
                }
            }
    }
    __syncthreads();

    {
        int row = tid >> 2, c = tid & 3;
        float m = -1e30f;
        for (int i = c; i < SCW; i += 4) m = fmaxf(m, Sc[row * SCW + i]);
        m = fmaxf(m, __shfl_xor(m, 1, 4));
        m = fmaxf(m, __shfl_xor(m, 2, 4));
        float s = 0.f;
        for (int i = c; i < SCW; i += 4) {
            float e = __expf(Sc[row * SCW + i] - m);
            Sc[row * SCW + i] = e;
            s += e;
        }
        s += __shfl_xor(s, 1, 4);
        s += __shfl_xor(s, 2, 4);
        if (c == 0) linv[row] = 1.0f / s;
    }

    f32x4 pv[2][2];
    #pragma unroll
    for (int mi = 0; mi < 2; mi++)
        #pragma unroll
        for (int ni = 0; ni < 2; ni++)
            #pragma unroll
            for (int j = 0; j < 4; j++) pv[mi][ni][j] = 0.f;

    for (int kt = 0; kt < 4; kt++) {
        __syncthreads();
        {
            int s = tid >> 2, c2 = tid & 3;
            int k = kt*64 + s; if (k > SS-1) k = SS-1;
            const bf16_t* vr = qkv + ((size_t)(b*SS + k))*QKVN + 1536 + hh*64;
            bf16x8 v0 = *(const bf16x8*)(vr + c2*16);
            bf16x8 v1 = *(const bf16x8*)(vr + c2*16 + 8);
            #pragma unroll
            for (int j = 0; j < 8; j++) {
                KV[(c2*16 + j) * 68 + s]     = v0[j];
                KV[(c2*16 + 8 + j) * 68 + s] = v1[j];
            }
        }
        __syncthreads();
        #pragma unroll
        for (int ks = 0; ks < 2; ks++) {
            int s0 = kt*64 + ks*32;
            if (s0 > SS-1) continue;
            bf16x8 af[2], bfr[2];
            #pragma unroll
            for (int mi = 0; mi < 2; mi++) {
                int qr = wm + mi * 16 + fr;
                const float* p = &Sc[qr * SCW + s0 + fs * 8];
                af[mi] = cvt8(*(const float4*)p, *(const float4*)(p + 4));
            }
            #pragma unroll
            for (int ni = 0; ni < 2; ni++) {
                int d = wn + ni * 16 + fr;
                bfr[ni] = *(bf16x8*)&KV[d * 68 + ks*32 + fs*8];
            }
            #pragma unroll
            for (int mi = 0; mi < 2; mi++)
                #pragma unroll
                for (int ni = 0; ni < 2; ni++)
                    pv[mi][ni] = __builtin_amdgcn_mfma_f32_16x16x32_bf16(af[mi], bfr[ni], pv[mi][ni], 0, 0, 0);
        }
    }

    #pragma unroll
    for (int mi = 0; mi < 2; mi++)
        #pragma unroll
        for (int j = 0; j < 4; j++) {
            int qr = wm + mi * 16 + fs * 4 + j;
            int q = qt*64 + qr;
            if (q > SS-1) continue;
            float il = linv[qr];
            #pragma unroll
            for (int ni = 0; ni < 2; ni++) {
                int d = wn + ni * 16 + fr;
                ob[((size_t)(b*SS + q))*DD + hh*64 + d] = (bf16_t)(pv[mi][ni][j] * il);
            }
        }
}

// ---------------- classifier head ----------------
__global__ void head_kernel(const float* __restrict__ h, const float* __restrict__ hw,
                            const float* __restrict__ hb, float* __restrict__ out)
{
    int i = blockIdx.x * 256 + threadIdx.x;
    if (i >= BB * 1000) return;
    int b = i & 7, n = i >> 3;
    const float4* hr = (const float4*)(h + (size_t)(b * SS) * DD);
    const float4* wr = (const float4*)(hw + (size_t)n * DD);
    float s = 0.f;
    #pragma unroll 4
    for (int k = 0; k < DD/4; k++) {
        float4 a = hr[k], wv = wr[k];
        s += a.x*wv.x + a.y*wv.y + a.z*wv.z + a.w*wv.w;
    }
    out[b * 1000 + n] = s + hb[n];
}

extern "C" void kernel_launch(void* const* d_in, const int* in_sizes, int n_in,
                              void* d_out, int out_size, void* d_ws, size_t ws_size,
                              hipStream_t stream) {
    const float* x          = (const float*)d_in[0];
    const float* patch_w    = (const float*)d_in[1];
    const float* patch_b    = (const float*)d_in[2];
    const float* cls_token  = (const float*)d_in[3];
    const float* pos_embed  = (const float*)d_in[4];
    const float* ln1_g      = (const float*)d_in[5];
    const float* ln1_b      = (const float*)d_in[6];
    const float* ln2_g      = (const float*)d_in[7];
    const float* ln2_b      = (const float*)d_in[8];
    const float* attn_in_w  = (const float*)d_in[9];
    const float* attn_in_b  = (const float*)d_in[10];
    const float* attn_out_w = (const float*)d_in[11];
    const float* attn_out_b = (const float*)d_in[12];
    const float* gate_w     = (const float*)d_in[13];
    const float* gate_b     = (const float*)d_in[14];
    const float* w1         = (const float*)d_in[15];
    const float* b1         = (const float*)d_in[16];
    const float* w2         = (const float*)d_in[17];
    const float* b2         = (const float*)d_in[18];
    const float* head_w     = (const float*)d_in[19];
    const float* head_b     = (const float*)d_in[20];
    float* out = (float*)d_out;

    char* wsb = (char*)d_ws;
    auto alloc = [&](size_t bytes) { char* p = wsb; wsb += (bytes + 63) & ~63ULL; return p; };
    bf16_t* Xp     = (bf16_t*)alloc((size_t)MPE * DD * 2);
    float*  h      = (float*) alloc((size_t)MT * DD * 4);
    bf16_t* qn_bf  = (bf16_t*)alloc((size_t)MT * DD * 2);
    bf16_t* h_bf   = (bf16_t*)alloc((size_t)MT * DD * 2);
    bf16_t* qkv_bf = (bf16_t*)alloc((size_t)MT * QKVN * 2);
    bf16_t* ob_bf  = (bf16_t*)alloc((size_t)MT * DD * 2);
    bf16_t* yb_bf  = (bf16_t*)alloc((size_t)MT * DD * 2);
    bf16_t* hd_bf  = (bf16_t*)alloc((size_t)MT * HHID * 2);
    float*  gv     = (float*) alloc((size_t)MT * 4);
    int*    cnt    = (int*)   alloc(12 * NEXP * 4);
    int*    idxb   = (int*)   alloc((size_t)12 * NEXP * MT * 4);

    dim3 blk(256);
    dim3 blk512(512);
    const int NOSPLIT = 1 << 30;

    init_misc<<<24, blk, 0, stream>>>(cls_token, pos_embed, h, h_bf, cnt);
    gather_patches<<<(MPE*DD + 255)/256, blk, 0, stream>>>(x, Xp);
    // patch embed -> h rows s>=1 directly (bias=patch_b, pos via gv slot)
    gemm_bf16<64,64,32,32,7,0><<<dim3(12, 25, 1), blk, 0, stream>>>(
        Xp, nullptr, NOSPLIT, patch_w, patch_b, h, h_bf, nullptr, nullptr, pos_embed, MPE, DD, DD);

    for (int i = 0; i < 12; i++) {
        const float* aw    = attn_in_w  + (size_t)i * QKVN * DD;
        const float* ow    = attn_out_w + (size_t)i * DD * DD;
        const float* w1l   = w1 + (size_t)i * NEXP * DD * HHID;
        const float* w2l   = w2 + (size_t)i * NEXP * HHID * DD;
        const float* ab    = attn_in_b  + (size_t)i * QKVN;
        const float* obias = attn_out_b + (size_t)i * DD;
        const float* l1g = ln1_g + (size_t)i * DD;
        const float* l1b = ln1_b + (size_t)i * DD;
        const float* l2g = ln2_g + (size_t)i * DD;
        const float* l2b = ln2_b + (size_t)i * DD;
        const float* gw  = gate_w + (size_t)i * NEXP * DD;
        const float* gb  = gate_b + (size_t)i * NEXP;
        const float* b1l = b1 + (size_t)i * NEXP * HHID;
        const float* b2l = b2 + (size_t)i * NEXP * DD;
        int* cnt_i  = cnt  + i * NEXP;
        int* idxb_i = idxb + (size_t)i * NEXP * MT;

        ln1_kernel<<<dim3((MT*64 + 255)/256), blk, 0, stream>>>(h, l1g, l1b, qn_bf);
        // merged q|kv projection: n0 < 768 uses qn_bf, else h_bf; B = attn_in_w fp32 [2304,768]
        gemm_bf16<128,64,64,32,5,0><<<dim3(QKVN/64, 13, 1), blk, 0, stream>>>(
            qn_bf, h_bf, DD, aw, ab, nullptr, qkv_bf, nullptr, nullptr, nullptr, MT, QKVN, DD);
        attn_kernel<<<dim3(4, 12, BB), blk, 0, stream>>>(qkv_bf, ob_bf);
        gemm_bf16<64,64,32,32,2,0><<<dim3(12, 25, 1), blk, 0, stream>>>(
            ob_bf, nullptr, NOSPLIT, ow, obias, h, nullptr, nullptr, nullptr, nullptr, MT, DD, DD);
        ln2_gate_kernel<<<dim3((MT*64 + 255)/256), blk, 0, stream>>>(
            h, l2g, l2b, gw, gb, yb_bf, gv, cnt_i, idxb_i);
        // moe1: B = w1[i] fp32 [768,3072] per expert, transposed in-flight (TN, vectorized)
        gemm_bf16<128,128,64,32,3,1><<<dim3(HHID/128, 13, NEXP), blk512, 0, stream>>>(
            yb_bf, nullptr, NOSPLIT, w1l, b1l, nullptr, hd_bf, cnt_i, idxb_i, nullptr, MT, HHID, DD);
        // moe2: B = w2[i] fp32 [3072,768] per expert (TN, vectorized)
        gemm_bf16<64,64,32,32,4,1><<<dim3(12, 25, NEXP), blk, 0, stream>>>(
            hd_bf, nullptr, NOSPLIT, w2l, b2l, h, h_bf, cnt_i, idxb_i, gv, MT, DD, HHID);
    }

    head_kernel<<<(BB*1000 + 255)/256, blk, 0, stream>>>(h, head_w, head_b, out);
}

// Round 13
// 2139.295 us; speedup vs baseline: 1.0565x; 1.0490x over previous
//
#include <hip/hip_runtime.h>
#include <math.h>

// MoE ViT forward. Best-measured configuration (R7, 2139.6 us): 2-barrier
// bf16-MFMA GEMMs, fp32 weights staged directly (NT and TN layouts), bf16
// activations via global_load_lds, MFMA attention, wave-per-token LayerNorms.
// B=8, S=197, D=768, NH=12, HD=64, E=4, HID=3072, DEPTH=12, NC=1000

#define BB 8
#define SS 197
#define DD 768
#define MT (BB*SS)      // 1576 tokens
#define NPATCH 196
#define MPE (BB*NPATCH) // 1568
#define HHID 3072
#define NEXP 4
#define QKVN 2304
#define SCW 228         // attn score-row stride

typedef __bf16 bf16_t;
typedef bf16_t bf16x4 __attribute__((ext_vector_type(4)));
typedef bf16_t bf16x8 __attribute__((ext_vector_type(8)));
typedef float  f32x4  __attribute__((ext_vector_type(4)));

__device__ __forceinline__ void gload16(const bf16_t* g, bf16_t* l) {
    __builtin_amdgcn_global_load_lds(
        (const __attribute__((address_space(1))) unsigned int*)g,
        (__attribute__((address_space(3))) unsigned int*)l,
        16, 0, 0);
}

__device__ __forceinline__ bf16x8 cvt8(float4 a, float4 b) {
    bf16x8 o;
    o[0]=(bf16_t)a.x; o[1]=(bf16_t)a.y; o[2]=(bf16_t)a.z; o[3]=(bf16_t)a.w;
    o[4]=(bf16_t)b.x; o[5]=(bf16_t)b.y; o[6]=(bf16_t)b.z; o[7]=(bf16_t)b.w;
    return o;
}

// ---------------- patch gather ----------------
__global__ void gather_patches(const float* __restrict__ x, bf16_t* __restrict__ Xp) {
    int i = blockIdx.x * 256 + threadIdx.x;
    if (i >= MPE * DD) return;
    int k = i % DD;
    int m = i / DD;
    int pw = k & 15, ph = (k >> 4) & 15, cin = k >> 8;
    int px = m % 14, py = (m / 14) % 14, b = m / NPATCH;
    int row = py * 16 + ph, col = px * 16 + pw;
    Xp[i] = (bf16_t)x[((size_t)(b * 3 + cin) * 224 + row) * 224 + col];
}

// ---------------- init: zero cnt + cls rows of h ----------------
__global__ void init_misc(const float* __restrict__ cls, const float* __restrict__ pos,
                          float* __restrict__ h, bf16_t* __restrict__ hb, int* __restrict__ cnt) {
    int i = blockIdx.x * 256 + threadIdx.x;
    if (i < 12*NEXP) cnt[i] = 0;
    if (i < BB * DD) {
        int b = i / DD, d = i % DD;
        float v = cls[d] + pos[d];
        size_t o = (size_t)(b * SS) * DD + d;
        h[o] = v;
        hb[o] = (bf16_t)v;
    }
}

// ---------------- unified bf16-MFMA GEMM, fp32-B direct staging ----------------
// C = A[M,K](bf16) @ B^T, B fp32: BL=0 -> [N,K] row-major; BL=1 -> [K,N] (transposed in-flight)
// MODE 2: fp32 C += v+bias; 3: gather, bf16 gelu(v+bias); 4: gather, fp32 C += (v+bias)*gv + bf16 mirror;
// MODE 5: bf16 store v+bias; 7: patch-embed: h/h_bf row-remapped store of v+bias+pos (pos via gv)
template<int BM, int BN, int WM, int WN, int MODE, int BL>
__global__ __launch_bounds__((BM/WM)*(BN/WN)*64) void gemm_bf16(
    const bf16_t* __restrict__ A, const bf16_t* __restrict__ A2, int nsplit,
    const float* __restrict__ Bw,
    const float* __restrict__ bias, float* __restrict__ C, bf16_t* __restrict__ Cb,
    const int* __restrict__ cnt, const int* __restrict__ idx,
    const float* __restrict__ gv, int M, int N, int K)
{
    constexpr int NW  = (BM/WM)*(BN/WN);
    constexpr int NTH = NW * 64;
    constexpr int WNC = BN/WN;
    constexpr int MI  = WM/16;
    constexpr int NI  = WN/16;
    constexpr int IA  = (BM/8)/NW;
    constexpr int BT  = (BN*8)/NTH;      // B staging tasks per thread
    constexpr bool GATHER = (MODE == 3 || MODE == 4);

    int z = blockIdx.z;
    int count = GATHER ? cnt[z] : M;
    int m0 = blockIdx.y * BM;
    if (m0 >= count) return;
    int n0 = blockIdx.x * BN;
    if (n0 >= nsplit) A = A2;
    Bw += (size_t)z * N * K;
    const float* biasz = bias ? (bias + (size_t)z * N) : nullptr;

    __shared__ bf16_t As[2][BM * 64];
    __shared__ bf16_t Bs[2][BN * 64];
    __shared__ int toks[BM];

    int tid = threadIdx.x, lane = tid & 63, w = tid >> 6;
    if (tid < BM) {
        int mm = m0 + tid;
        if (mm > count - 1) mm = count - 1;
        toks[tid] = GATHER ? idx[z * MT + mm] : mm;
    }
    __syncthreads();

    int wm = (w / WNC) * WM, wn = (w % WNC) * WN;
    int fr = lane & 15, fs = lane >> 4;

    f32x4 acc[MI][NI];
    #pragma unroll
    for (int mi = 0; mi < MI; mi++)
        #pragma unroll
        for (int ni = 0; ni < NI; ni++)
            #pragma unroll
            for (int j = 0; j < 4; j++) acc[mi][ni][j] = 0.f;

    int nk = K >> 6;
    int srow = lane >> 3, scc = lane & 7;

    float4 bA[BT], bB[BT];     // NT staging regs
    float  bt[BT][8];          // TN staging regs

    #define A_STAGE(buf, k0)                                                            \
        {                                                                               \
            _Pragma("unroll")                                                           \
            for (int i = 0; i < IA; i++) {                                              \
                int blk = i*NW + w;                                                     \
                int row = blk*8 + srow;                                                 \
                const bf16_t* s = A + (size_t)toks[row] * K + (k0) + ((scc ^ (row & 7)) << 3); \
                gload16(s, &As[buf][blk * 512]);                                        \
            }                                                                           \
        }

    #define B_LOAD(k0)                                                                  \
        {                                                                               \
            _Pragma("unroll")                                                           \
            for (int i = 0; i < BT; i++) {                                              \
                int task = i*NTH + tid;                                                 \
                if (BL == 0) {                                                          \
                    int row = task >> 3, sl = task & 7;                                 \
                    const float* s = Bw + (size_t)(n0 + row) * K + (k0) + sl*8;         \
                    bA[i] = *(const float4*)s;                                          \
                    bB[i] = *(const float4*)(s + 4);                                    \
                } else {                                                                \
                    int n = task & (BN-1), sl = task / BN;                              \
                    const float* s = Bw + (size_t)((k0) + sl*8) * N + n0 + n;           \
                    _Pragma("unroll")                                                   \
                    for (int j = 0; j < 8; j++) bt[i][j] = s[(size_t)j * N];            \
                }                                                                       \
            }                                                                           \
        }

    #define B_WRITE(buf)                                                                \
        {                                                                               \
            _Pragma("unroll")                                                           \
            for (int i = 0; i < BT; i++) {                                              \
                int task = i*NTH + tid;                                                 \
                int row, sl;                                                            \
                bf16x8 o;                                                               \
                if (BL == 0) {                                                          \
                    row = task >> 3; sl = task & 7;                                     \
                    o = cvt8(bA[i], bB[i]);                                             \
                } else {                                                                \
                    row = task & (BN-1); sl = task / BN;                                \
                    _Pragma("unroll")                                                   \
                    for (int j = 0; j < 8; j++) o[j] = (bf16_t)bt[i][j];                \
                }                                                                       \
                *(bf16x8*)&Bs[buf][row * 64 + ((sl ^ (row & 7)) << 3)] = o;             \
            }                                                                           \
        }

    A_STAGE(0, 0);
    B_LOAD(0);
    B_WRITE(0);
    __syncthreads();
    int cur = 0;
    for (int t = 0; t < nk; t++) {
        if (t + 1 < nk) { A_STAGE(cur ^ 1, (t + 1) << 6); B_LOAD((t + 1) << 6); }
        #pragma unroll
        for (int ks = 0; ks < 2; ks++) {
            bf16x8 af[MI], bfr[NI];
            #pragma unroll
            for (int mi = 0; mi < MI; mi++) {
                int r = wm + mi * 16 + fr;
                af[mi] = *(bf16x8*)&As[cur][r * 64 + (((fs + ks*4) ^ (r & 7)) << 3)];
            }
            #pragma unroll
            for (int ni = 0; ni < NI; ni++) {
                int r = wn + ni * 16 + fr;
                bfr[ni] = *(bf16x8*)&Bs[cur][r * 64 + (((fs + ks*4) ^ (r & 7)) << 3)];
            }
            #pragma unroll
            for (int mi = 0; mi < MI; mi++)
                #pragma unroll
                for (int ni = 0; ni < NI; ni++)
                    acc[mi][ni] = __builtin_amdgcn_mfma_f32_16x16x32_bf16(af[mi], bfr[ni], acc[mi][ni], 0, 0, 0);
        }
        if (t + 1 < nk) B_WRITE(cur ^ 1);
        __syncthreads();
        cur ^= 1;
    }
    #undef A_STAGE
    #undef B_LOAD
    #undef B_WRITE

    #pragma unroll
    for (int mi = 0; mi < MI; mi++) {
        #pragma unroll
        for (int j = 0; j < 4; j++) {
            int rr = wm + mi * 16 + fs * 4 + j;
            if (m0 + rr >= count) continue;
            int crow = toks[rr];
            #pragma unroll
            for (int ni = 0; ni < NI; ni++) {
                int col = n0 + wn + ni * 16 + fr;
                float v = acc[mi][ni][j];
                if (MODE >= 2) v += biasz[col];
                if (MODE == 2) {
                    C[(size_t)crow * N + col] += v;
                } else if (MODE == 3) {
                    float g = 0.5f * v * (1.0f + tanhf(0.7978845608028654f * (v + 0.044715f * v * v * v)));
                    Cb[(size_t)crow * N + col] = (bf16_t)g;
                } else if (MODE == 4) {
                    float* p = &C[(size_t)crow * N + col];
                    float nv = *p + v * gv[crow];
                    *p = nv;
                    Cb[(size_t)crow * N + col] = (bf16_t)nv;
                } else if (MODE == 5) {
                    Cb[(size_t)crow * N + col] = (bf16_t)v;
                } else if (MODE == 7) {
                    int bb = crow / NPATCH, p = crow - bb * NPATCH;
                    size_t o = ((size_t)(bb * SS + 1 + p)) * DD + col;
                    float vv = v + gv[(size_t)(1 + p) * DD + col];   // gv == pos_embed
                    C[o] = vv;
                    Cb[o] = (bf16_t)vv;
                }
            }
        }
    }
}

// ---------------- LN1: one wave per token, writes qn bf16 ----------------
__global__ __launch_bounds__(256) void ln1_kernel(const float* __restrict__ x,
                                                  const float* __restrict__ g,
                                                  const float* __restrict__ b,
                                                  bf16_t* __restrict__ qn)
{
    int wid = (blockIdx.x * 256 + threadIdx.x) >> 6;
    if (wid >= MT) return;
    int lane = threadIdx.x & 63;
    const float4* xr = (const float4*)(x + (size_t)wid * DD);
    float4 v0 = xr[lane], v1 = xr[lane + 64], v2 = xr[lane + 128];
    float s = v0.x+v0.y+v0.z+v0.w + v1.x+v1.y+v1.z+v1.w + v2.x+v2.y+v2.z+v2.w;
    #pragma unroll
    for (int o = 32; o > 0; o >>= 1) s += __shfl_xor(s, o);
    float mean = s * (1.0f/DD);
    float s2 = 0.f;
    #pragma unroll
    for (int c = 0; c < 3; c++) {
        float4 v = c == 0 ? v0 : (c == 1 ? v1 : v2);
        float dx = v.x-mean, dy = v.y-mean, dz = v.z-mean, dw = v.w-mean;
        s2 += dx*dx + dy*dy + dz*dz + dw*dw;
    }
    #pragma unroll
    for (int o = 32; o > 0; o >>= 1) s2 += __shfl_xor(s2, o);
    float rs = rsqrtf(s2 * (1.0f/DD) + 1e-5f);
    const float4* gr = (const float4*)g;
    const float4* br = (const float4*)b;
    #pragma unroll
    for (int c = 0; c < 3; c++) {
        float4 v = c == 0 ? v0 : (c == 1 ? v1 : v2);
        float4 gg = gr[lane + 64*c], bb = br[lane + 64*c];
        bf16x4 o;
        o[0] = (bf16_t)((v.x - mean) * rs * gg.x + bb.x);
        o[1] = (bf16_t)((v.y - mean) * rs * gg.y + bb.y);
        o[2] = (bf16_t)((v.z - mean) * rs * gg.z + bb.z);
        o[3] = (bf16_t)((v.w - mean) * rs * gg.w + bb.w);
        *(bf16x4*)(qn + (size_t)wid * DD + (lane + 64*c) * 4) = o;
    }
}

// ---------------- LN2 + gate: one wave per token ----------------
__global__ __launch_bounds__(256) void ln2_gate_kernel(const float* __restrict__ x,
                                                       const float* __restrict__ g,
                                                       const float* __restrict__ b,
                                                       const float* __restrict__ gw,
                                                       const float* __restrict__ gb,
                                                       bf16_t* __restrict__ yb,
                                                       float* __restrict__ gv,
                                                       int* __restrict__ cnt,
                                                       int* __restrict__ idxb)
{
    int wid = (blockIdx.x * 256 + threadIdx.x) >> 6;
    if (wid >= MT) return;
    int lane = threadIdx.x & 63;
    const float4* xr = (const float4*)(x + (size_t)wid * DD);
    float4 v0 = xr[lane], v1 = xr[lane + 64], v2 = xr[lane + 128];
    float s = v0.x+v0.y+v0.z+v0.w + v1.x+v1.y+v1.z+v1.w + v2.x+v2.y+v2.z+v2.w;
    #pragma unroll
    for (int o = 32; o > 0; o >>= 1) s += __shfl_xor(s, o);
    float mean = s * (1.0f/DD);
    float s2 = 0.f;
    #pragma unroll
    for (int c = 0; c < 3; c++) {
        float4 v = c == 0 ? v0 : (c == 1 ? v1 : v2);
        float dx = v.x-mean, dy = v.y-mean, dz = v.z-mean, dw = v.w-mean;
        s2 += dx*dx + dy*dy + dz*dz + dw*dw;
    }
    #pragma unroll
    for (int o = 32; o > 0; o >>= 1) s2 += __shfl_xor(s2, o);
    float rs = rsqrtf(s2 * (1.0f/DD) + 1e-5f);
    const float4* gr = (const float4*)g;
    const float4* br = (const float4*)b;
    float p0 = 0.f, p1 = 0.f, p2 = 0.f, p3 = 0.f;
    #pragma unroll
    for (int c = 0; c < 3; c++) {
        float4 v = c == 0 ? v0 : (c == 1 ? v1 : v2);
        float4 gg = gr[lane + 64*c], bb = br[lane + 64*c];
        float y0 = (v.x - mean) * rs * gg.x + bb.x;
        float y1 = (v.y - mean) * rs * gg.y + bb.y;
        float y2 = (v.z - mean) * rs * gg.z + bb.z;
        float y3 = (v.w - mean) * rs * gg.w + bb.w;
        bf16x4 o; o[0]=(bf16_t)y0; o[1]=(bf16_t)y1; o[2]=(bf16_t)y2; o[3]=(bf16_t)y3;
        *(bf16x4*)(yb + (size_t)wid * DD + (lane + 64*c) * 4) = o;
        int off = lane + 64*c;
        float4 w0 = ((const float4*)(gw          ))[off];
        float4 w1v = ((const float4*)(gw +   DD  ))[off];
        float4 w2v = ((const float4*)(gw + 2*DD  ))[off];
        float4 w3v = ((const float4*)(gw + 3*DD  ))[off];
        p0 += y0*w0.x + y1*w0.y + y2*w0.z + y3*w0.w;
        p1 += y0*w1v.x + y1*w1v.y + y2*w1v.z + y3*w1v.w;
        p2 += y0*w2v.x + y1*w2v.y + y2*w2v.z + y3*w2v.w;
        p3 += y0*w3v.x + y1*w3v.y + y2*w3v.z + y3*w3v.w;
    }
    #pragma unroll
    for (int o = 32; o > 0; o >>= 1) {
        p0 += __shfl_xor(p0, o); p1 += __shfl_xor(p1, o);
        p2 += __shfl_xor(p2, o); p3 += __shfl_xor(p3, o);
    }
    if (lane == 0) {
        float l0 = p0 + gb[0], l1 = p1 + gb[1], l2 = p2 + gb[2], l3 = p3 + gb[3];
        int top = 0; float best = l0;
        if (l1 > best) { best = l1; top = 1; }
        if (l2 > best) { best = l2; top = 2; }
        if (l3 > best) { best = l3; top = 3; }
        float Z = __expf(l0-best) + __expf(l1-best) + __expf(l2-best) + __expf(l3-best);
        gv[wid] = 1.0f / Z;
        int pos = atomicAdd(&cnt[top], 1);
        idxb[top * MT + pos] = wid;
    }
}

// ---------------- MFMA attention: block per (q-tile, head, batch) ----------------
__global__ __launch_bounds__(256) void attn_kernel(const bf16_t* __restrict__ qkv,
                                                   bf16_t* __restrict__ ob)
{
    int qt = blockIdx.x, hh = blockIdx.y, b = blockIdx.z;
    __shared__ bf16_t Qs[64 * 64];
    __shared__ bf16_t KV[64 * 68];
    __shared__ float  Sc[64 * SCW];
    __shared__ float  linv[64];

    int tid = threadIdx.x, lane = tid & 63, w = tid >> 6;
    int wm = (w >> 1) * 32, wn = (w & 1) * 32;
    int fr = lane & 15, fs = lane >> 4;

    #pragma unroll
    for (int it = 0; it < 2; it++) {
        int row = 8*(it*4 + w) + (lane >> 3), cc = lane & 7;
        int q = qt*64 + row; if (q > SS-1) q = SS-1;
        const bf16_t* src = qkv + ((size_t)(b*SS + q))*QKVN + hh*64 + ((cc ^ (row & 7)) << 3);
        gload16(src, &Qs[(it*4 + w) * 512]);
    }

    for (int kt = 0; kt < 4; kt++) {
        __syncthreads();
        #pragma unroll
        for (int it = 0; it < 2; it++) {
            int row = 8*(it*4 + w) + (lane >> 3), cc = lane & 7;
            int k = kt*64 + row; if (k > SS-1) k = SS-1;
            const bf16_t* src = qkv + ((size_t)(b*SS + k))*QKVN + 768 + hh*64 + ((cc ^ (row & 7)) << 3);
            gload16(src, &KV[(it*4 + w) * 512]);
        }
        __syncthreads();
        f32x4 acc[2][2];
        #pragma unroll
        for (int mi = 0; mi < 2; mi++)
            #pragma unroll
            for (int ni = 0; ni < 2; ni++)
                #pragma unroll
                for (int j = 0; j < 4; j++) acc[mi][ni][j] = 0.f;
        #pragma unroll
        for (int ks = 0; ks < 2; ks++) {
            bf16x8 af[2], bfr[2];
            #pragma unroll
            for (int mi = 0; mi < 2; mi++) {
                int r = wm + mi * 16 + fr;
                af[mi] = *(bf16x8*)&Qs[r * 64 + (((fs + ks*4) ^ (r & 7)) << 3)];
            }
            #pragma unroll
            for (int ni = 0; ni < 2; ni++) {
                int r = wn + ni * 16 + fr;
                bfr[ni] = *(bf16x8*)&KV[r * 64 + (((fs + ks*4) ^ (r & 7)) << 3)];
            }
            #pragma unroll
            for (int mi = 0; mi < 2; mi++)
                #pragma unroll
                for (int ni = 0; ni < 2; ni++)
                    acc[mi][ni] = __builtin_amdgcn_mfma_f32_16x16x32_bf16(af[mi], bfr[ni], acc[mi][ni], 0, 0, 0);
        }
        #pragma unroll
        for (int mi = 0; mi < 2; mi++)
            #pragma unroll
            for (int j = 0; j < 4; j++) {
                int qr = wm + mi * 16 + fs * 4 + j;
                #pragma unroll
                for (int ni = 0; ni < 2; ni++) {
                    int col = kt*64 + wn + ni * 16 + fr;
                    if (col < SCW) {
                        float v = acc[mi][ni][j] * 0.125f;
                        if (col > SS-1) v = -1e30f;
                        Sc[qr * SCW + col] = v;
                    }
                }
            }
    }
    __syncthreads();

    {
        int row = tid >> 2, c = tid & 3;
        float m = -1e30f;
        for (int i = c; i < SCW; i += 4) m = fmaxf(m, Sc[row * SCW + i]);
        m = fmaxf(m, __shfl_xor(m, 1, 4));
        m = fmaxf(m, __shfl_xor(m, 2, 4));
        float s = 0.f;
        for (int i = c; i < SCW; i += 4) {
            float e = __expf(Sc[row * SCW + i] - m);
            Sc[row * SCW + i] = e;
            s += e;
        }
        s += __shfl_xor(s, 1, 4);
        s += __shfl_xor(s, 2, 4);
        if (c == 0) linv[row] = 1.0f / s;
    }

    f32x4 pv[2][2];
    #pragma unroll
    for (int mi = 0; mi < 2; mi++)
        #pragma unroll
        for (int ni = 0; ni < 2; ni++)
            #pragma unroll
            for (int j = 0; j < 4; j++) pv[mi][ni][j] = 0.f;

    for (int kt = 0; kt < 4; kt++) {
        __syncthreads();
        {
            int s = tid >> 2, c2 = tid & 3;
            int k = kt*64 + s; if (k > SS-1) k = SS-1;
            const bf16_t* vr = qkv + ((size_t)(b*SS + k))*QKVN + 1536 + hh*64;
            bf16x8 v0 = *(const bf16x8*)(vr + c2*16);
            bf16x8 v1 = *(const bf16x8*)(vr + c2*16 + 8);
            #pragma unroll
            for (int j = 0; j < 8; j++) {
                KV[(c2*16 + j) * 68 + s]     = v0[j];
                KV[(c2*16 + 8 + j) * 68 + s] = v1[j];
            }
        }
        __syncthreads();
        #pragma unroll
        for (int ks = 0; ks < 2; ks++) {
            int s0 = kt*64 + ks*32;
            if (s0 > SS-1) continue;
            bf16x8 af[2], bfr[2];
            #pragma unroll
            for (int mi = 0; mi < 2; mi++) {
                int qr = wm + mi * 16 + fr;
                const float* p = &Sc[qr * SCW + s0 + fs * 8];
                af[mi] = cvt8(*(const float4*)p, *(const float4*)(p + 4));
            }
            #pragma unroll
            for (int ni = 0; ni < 2; ni++) {
                int d = wn + ni * 16 + fr;
                bfr[ni] = *(bf16x8*)&KV[d * 68 + ks*32 + fs*8];
            }
            #pragma unroll
            for (int mi = 0; mi < 2; mi++)
                #pragma unroll
                for (int ni = 0; ni < 2; ni++)
                    pv[mi][ni] = __builtin_amdgcn_mfma_f32_16x16x32_bf16(af[mi], bfr[ni], pv[mi][ni], 0, 0, 0);
        }
    }

    #pragma unroll
    for (int mi = 0; mi < 2; mi++)
        #pragma unroll
        for (int j = 0; j < 4; j++) {
            int qr = wm + mi * 16 + fs * 4 + j;
            int q = qt*64 + qr;
            if (q > SS-1) continue;
            float il = linv[qr];
            #pragma unroll
            for (int ni = 0; ni < 2; ni++) {
                int d = wn + ni * 16 + fr;
                ob[((size_t)(b*SS + q))*DD + hh*64 + d] = (bf16_t)(pv[mi][ni][j] * il);
            }
        }
}

// ---------------- classifier head ----------------
__global__ void head_kernel(const float* __restrict__ h, const float* __restrict__ hw,
                            const float* __restrict__ hb, float* __restrict__ out)
{
    int i = blockIdx.x * 256 + threadIdx.x;
    if (i >= BB * 1000) return;
    int b = i & 7, n = i >> 3;
    const float4* hr = (const float4*)(h + (size_t)(b * SS) * DD);
    const float4* wr = (const float4*)(hw + (size_t)n * DD);
    float s = 0.f;
    #pragma unroll 4
    for (int k = 0; k < DD/4; k++) {
        float4 a = hr[k], wv = wr[k];
        s += a.x*wv.x + a.y*wv.y + a.z*wv.z + a.w*wv.w;
    }
    out[b * 1000 + n] = s + hb[n];
}

extern "C" void kernel_launch(void* const* d_in, const int* in_sizes, int n_in,
                              void* d_out, int out_size, void* d_ws, size_t ws_size,
                              hipStream_t stream) {
    const float* x          = (const float*)d_in[0];
    const float* patch_w    = (const float*)d_in[1];
    const float* patch_b    = (const float*)d_in[2];
    const float* cls_token  = (const float*)d_in[3];
    const float* pos_embed  = (const float*)d_in[4];
    const float* ln1_g      = (const float*)d_in[5];
    const float* ln1_b      = (const float*)d_in[6];
    const float* ln2_g      = (const float*)d_in[7];
    const float* ln2_b      = (const float*)d_in[8];
    const float* attn_in_w  = (const float*)d_in[9];
    const float* attn_in_b  = (const float*)d_in[10];
    const float* attn_out_w = (const float*)d_in[11];
    const float* attn_out_b = (const float*)d_in[12];
    const float* gate_w     = (const float*)d_in[13];
    const float* gate_b     = (const float*)d_in[14];
    const float* w1         = (const float*)d_in[15];
    const float* b1         = (const float*)d_in[16];
    const float* w2         = (const float*)d_in[17];
    const float* b2         = (const float*)d_in[18];
    const float* head_w     = (const float*)d_in[19];
    const float* head_b     = (const float*)d_in[20];
    float* out = (float*)d_out;

    char* wsb = (char*)d_ws;
    auto alloc = [&](size_t bytes) { char* p = wsb; wsb += (bytes + 63) & ~63ULL; return p; };
    bf16_t* Xp     = (bf16_t*)alloc((size_t)MPE * DD * 2);
    float*  h      = (float*) alloc((size_t)MT * DD * 4);
    bf16_t* qn_bf  = (bf16_t*)alloc((size_t)MT * DD * 2);
    bf16_t* h_bf   = (bf16_t*)alloc((size_t)MT * DD * 2);
    bf16_t* qkv_bf = (bf16_t*)alloc((size_t)MT * QKVN * 2);
    bf16_t* ob_bf  = (bf16_t*)alloc((size_t)MT * DD * 2);
    bf16_t* yb_bf  = (bf16_t*)alloc((size_t)MT * DD * 2);
    bf16_t* hd_bf  = (bf16_t*)alloc((size_t)MT * HHID * 2);
    float*  gv     = (float*) alloc((size_t)MT * 4);
    int*    cnt    = (int*)   alloc(12 * NEXP * 4);
    int*    idxb   = (int*)   alloc((size_t)12 * NEXP * MT * 4);

    dim3 blk(256);
    dim3 blk512(512);
    const int NOSPLIT = 1 << 30;

    init_misc<<<24, blk, 0, stream>>>(cls_token, pos_embed, h, h_bf, cnt);
    gather_patches<<<(MPE*DD + 255)/256, blk, 0, stream>>>(x, Xp);
    // patch embed -> h rows s>=1 directly (bias=patch_b, pos via gv slot)
    gemm_bf16<64,64,32,32,7,0><<<dim3(12, 25, 1), blk, 0, stream>>>(
        Xp, nullptr, NOSPLIT, patch_w, patch_b, h, h_bf, nullptr, nullptr, pos_embed, MPE, DD, DD);

    for (int i = 0; i < 12; i++) {
        const float* aw    = attn_in_w  + (size_t)i * QKVN * DD;
        const float* ow    = attn_out_w + (size_t)i * DD * DD;
        const float* w1l   = w1 + (size_t)i * NEXP * DD * HHID;
        const float* w2l   = w2 + (size_t)i * NEXP * HHID * DD;
        const float* ab    = attn_in_b  + (size_t)i * QKVN;
        const float* obias = attn_out_b + (size_t)i * DD;
        const float* l1g = ln1_g + (size_t)i * DD;
        const float* l1b = ln1_b + (size_t)i * DD;
        const float* l2g = ln2_g + (size_t)i * DD;
        const float* l2b = ln2_b + (size_t)i * DD;
        const float* gw  = gate_w + (size_t)i * NEXP * DD;
        const float* gb  = gate_b + (size_t)i * NEXP;
        const float* b1l = b1 + (size_t)i * NEXP * HHID;
        const float* b2l = b2 + (size_t)i * NEXP * DD;
        int* cnt_i  = cnt  + i * NEXP;
        int* idxb_i = idxb + (size_t)i * NEXP * MT;

        ln1_kernel<<<dim3((MT*64 + 255)/256), blk, 0, stream>>>(h, l1g, l1b, qn_bf);
        // merged q|kv projection: n0 < 768 uses qn_bf, else h_bf; B = attn_in_w fp32 [2304,768]
        gemm_bf16<128,64,64,32,5,0><<<dim3(QKVN/64, 13, 1), blk, 0, stream>>>(
            qn_bf, h_bf, DD, aw, ab, nullptr, qkv_bf, nullptr, nullptr, nullptr, MT, QKVN, DD);
        attn_kernel<<<dim3(4, 12, BB), blk, 0, stream>>>(qkv_bf, ob_bf);
        gemm_bf16<64,64,32,32,2,0><<<dim3(12, 25, 1), blk, 0, stream>>>(
            ob_bf, nullptr, NOSPLIT, ow, obias, h, nullptr, nullptr, nullptr, nullptr, MT, DD, DD);
        ln2_gate_kernel<<<dim3((MT*64 + 255)/256), blk, 0, stream>>>(
            h, l2g, l2b, gw, gb, yb_bf, gv, cnt_i, idxb_i);
        // moe1: B = w1[i] fp32 [768,3072] per expert, transposed in-flight (TN)
        gemm_bf16<128,128,64,32,3,1><<<dim3(HHID/128, 13, NEXP), blk512, 0, stream>>>(
            yb_bf, nullptr, NOSPLIT, w1l, b1l, nullptr, hd_bf, cnt_i, idxb_i, nullptr, MT, HHID, DD);
        // moe2: B = w2[i] fp32 [3072,768] per expert (TN)
        gemm_bf16<64,64,32,32,4,1><<<dim3(12, 25, NEXP), blk, 0, stream>>>(
            hd_bf, nullptr, NOSPLIT, w2l, b2l, h, h_bf, cnt_i, idxb_i, gv, MT, DD, HHID);
    }

    head_kernel<<<(BB*1000 + 255)/256, blk, 0, stream>>>(h, head_w, head_b, out);
}